// Round 1
// baseline (263.435 us; speedup 1.0000x reference)
//
#include <hip/hip_runtime.h>
#include <math.h>

namespace {
constexpr int N_ = 2, C_ = 64, HR_ = 60, WR_ = 80, HW_ = HR_ * WR_; // 4800
constexpr int K_ = 1024, GS_ = 8, H_ = HR_ * GS_, W_ = WR_ * GS_;  // 480, 640
constexpr int KT_ = 8, HS_ = 4, SEG_ = HW_ / HS_;                  // 1200
constexpr float NEGBIG = -3.0e38f, POSBIG = 3.0e38f;
}

// Kernel A: bilinear sample desc1 at keypoints; one thread per (k, c).
// Also emits ||kp1_desc[k]||^2 (wave reduction; one wave == one keypoint)
// and the kp_grid coords with the reference's .at[:,0]/.at[:,1] quirk
// (only keypoints 0 and 1 are divided by GS).
__global__ __launch_bounds__(256) void k_sample(
    const float* __restrict__ kp1, const float* __restrict__ desc1,
    float* __restrict__ out_desc, float* __restrict__ kpd,
    float* __restrict__ ksq, float* __restrict__ kpgx, float* __restrict__ kpgy)
{
  int t = blockIdx.x * 256 + threadIdx.x;
  int k = t >> 6, c = t & 63;
  float bf = kp1[k * 4 + 0];
  float yr = kp1[k * 4 + 2];
  float xr = kp1[k * 4 + 3];
  int b = (int)bf;
  float x = fminf(fmaxf(xr * (1.0f / GS_), 0.0f), (float)(WR_ - 1));
  float y = fminf(fmaxf(yr * (1.0f / GS_), 0.0f), (float)(HR_ - 1));
  float x0f = floorf(x), y0f = floorf(y);
  float x1f = fminf(x0f + 1.0f, (float)(WR_ - 1));
  float y1f = fminf(y0f + 1.0f, (float)(HR_ - 1));
  float wx = x - x0f, wy = y - y0f;
  int x0 = (int)x0f, x1 = (int)x1f, y0 = (int)y0f, y1 = (int)y1f;
  const float* dbase = desc1 + ((size_t)b * C_ + c) * HW_;
  float v00 = dbase[y0 * WR_ + x0], v01 = dbase[y0 * WR_ + x1];
  float v10 = dbase[y1 * WR_ + x0], v11 = dbase[y1 * WR_ + x1];
  float v = (1.0f - wy) * ((1.0f - wx) * v00 + wx * v01)
          + wy * ((1.0f - wx) * v10 + wx * v11);
  out_desc[k * C_ + c] = v;
  kpd[k * C_ + c] = v;
  float sq = v * v;
  #pragma unroll
  for (int m = 1; m < 64; m <<= 1) sq += __shfl_xor(sq, m);
  if (c == 0) {
    ksq[k] = sq;
    // Reference quirk: kp_grid.at[:,0] / .at[:,1] index the KEYPOINT axis,
    // so only keypoints 0 and 1 get divided by GS.
    kpgx[k] = (k < 2) ? xr * (1.0f / GS_) : xr;
    kpgy[k] = (k < 2) ? yr * (1.0f / GS_) : yr;
  }
}

// Kernel B: per (n, hw): warped grid coords, visibility product over 8x8 cell,
// and ||desc2[n,:,hw]||^2.
__global__ __launch_bounds__(256) void k_prep(
    const float* __restrict__ desc2, const float* __restrict__ homo,
    const float* __restrict__ vis,
    float* __restrict__ wxa, float* __restrict__ wya,
    float* __restrict__ vma, float* __restrict__ dsa)
{
  int t = blockIdx.x * 256 + threadIdx.x;
  if (t >= N_ * HW_) return;
  int n = t / HW_, hw = t % HW_;
  int h = hw / WR_, w = hw % WR_;
  float gx = (float)(w * GS_ + GS_ / 2);
  float gy = (float)(h * GS_ + GS_ / 2);
  const float* hm = homo + n * 9;
  float w0 = fmaf(hm[0], gx, fmaf(hm[1], gy, hm[2]));
  float w1 = fmaf(hm[3], gx, fmaf(hm[4], gy, hm[5]));
  float w2 = fmaf(hm[6], gx, fmaf(hm[7], gy, hm[8]));
  wxa[t] = w0 / w2;
  wya[t] = w1 / w2;
  const float* vb = vis + (size_t)n * H_ * W_ + (size_t)(h * GS_) * W_ + w * GS_;
  float p = 1.0f;
  #pragma unroll
  for (int i = 0; i < GS_; i++)
    #pragma unroll
    for (int j = 0; j < GS_; j++) p *= vb[i * W_ + j];
  vma[t] = p;
  const float* d2 = desc2 + (size_t)n * C_ * HW_ + hw;
  float s = 0.0f;
  #pragma unroll
  for (int c = 0; c < C_; c++) { float dv = d2[c * HW_]; s = fmaf(dv, dv, s); }
  dsa[t] = s;
}

// Kernel C: main reduction. Block = (n, tile of 8 keypoints, 1/4 of hw).
// Each thread holds one desc2 column (64 floats) in registers; dots it against
// 8 LDS-resident keypoint descriptors. Tracks class-wise max/min of
// (||d2col||^2 - 2*dot); sqrt is deferred to the final kernel (monotone).
__global__ __launch_bounds__(256) void k_main(
    const float* __restrict__ desc2,
    const float* __restrict__ kpd, const float* __restrict__ kpgx,
    const float* __restrict__ kpgy,
    const float* __restrict__ wxa, const float* __restrict__ wya,
    const float* __restrict__ vma, const float* __restrict__ dsa,
    float* __restrict__ accA, float* __restrict__ accB,
    float* __restrict__ accC, float* __restrict__ accD)
{
  __shared__ float4 kpds[KT_][16];
  __shared__ float kpgxs[KT_], kpgys[KT_];
  __shared__ float red[4][32];
  int tid = threadIdx.x;
  int bx = blockIdx.x;
  int n = bx / ((K_ / KT_) * HS_);
  int rem = bx % ((K_ / KT_) * HS_);
  int kt = rem / HS_, hs = rem % HS_;
  int k0 = kt * KT_;

  ((float*)kpds)[tid] = kpd[k0 * C_ + tid];
  ((float*)kpds)[tid + 256] = kpd[k0 * C_ + tid + 256];
  if (tid < KT_) { kpgxs[tid] = kpgx[k0 + tid]; kpgys[tid] = kpgy[k0 + tid]; }
  __syncthreads();

  float mA[KT_], mB[KT_], mC[KT_], mD[KT_];
  #pragma unroll
  for (int k = 0; k < KT_; k++) { mA[k] = NEGBIG; mB[k] = NEGBIG; mC[k] = POSBIG; mD[k] = POSBIG; }

  const float* dbase = desc2 + (size_t)n * C_ * HW_;
  const float* wxp = wxa + n * HW_;
  const float* wyp = wya + n * HW_;
  const float* vmp = vma + n * HW_;
  const float* dsp = dsa + n * HW_;
  int hwb = hs * SEG_;

  for (int ch = 0; ch < 5; ++ch) {
    int off = ch * 256 + tid;
    bool valid = off < SEG_;
    int hw = hwb + (valid ? off : 0);
    float dcol[C_];
    #pragma unroll
    for (int c = 0; c < C_; c++) dcol[c] = dbase[c * HW_ + hw];
    float wxv = wxp[hw], wyv = wyp[hw], vmv = vmp[hw], dsv = dsp[hw];
    bool vm1 = vmv != 0.0f;
    #pragma unroll
    for (int k = 0; k < KT_; k++) {
      float s0 = 0.f, s1 = 0.f, s2 = 0.f, s3 = 0.f;
      #pragma unroll
      for (int q = 0; q < 16; q++) {
        float4 a = kpds[k][q];
        s0 = fmaf(a.x, dcol[4 * q + 0], s0);
        s1 = fmaf(a.y, dcol[4 * q + 1], s1);
        s2 = fmaf(a.z, dcol[4 * q + 2], s2);
        s3 = fmaf(a.w, dcol[4 * q + 3], s3);
      }
      float val = fmaf(-2.0f, (s0 + s1) + (s2 + s3), dsv);
      float dx = kpgxs[k] - wxv, dy = kpgys[k] - wyv;
      bool inside = fmaf(dx, dx, dy * dy) <= 56.25f;  // (GS-0.5)^2
      if (valid) {
        if (vm1 && !inside) mB[k] = fmaxf(mB[k], val);
        else                mA[k] = fmaxf(mA[k], val);
        if (vm1 && inside)  mD[k] = fminf(mD[k], val);
        else                mC[k] = fminf(mC[k], val);
      }
    }
  }

  // wave butterfly reduction (64 lanes)
  #pragma unroll
  for (int k = 0; k < KT_; k++) {
    #pragma unroll
    for (int m = 1; m < 64; m <<= 1) {
      mA[k] = fmaxf(mA[k], __shfl_xor(mA[k], m));
      mB[k] = fmaxf(mB[k], __shfl_xor(mB[k], m));
      mC[k] = fminf(mC[k], __shfl_xor(mC[k], m));
      mD[k] = fminf(mD[k], __shfl_xor(mD[k], m));
    }
  }
  int wave = tid >> 6, lane = tid & 63;
  if (lane == 0) {
    #pragma unroll
    for (int k = 0; k < KT_; k++) {
      red[wave][k]      = mA[k];
      red[wave][8 + k]  = mB[k];
      red[wave][16 + k] = mC[k];
      red[wave][24 + k] = mD[k];
    }
  }
  __syncthreads();
  if (tid < KT_) {
    int k = tid;
    float a = fmaxf(fmaxf(red[0][k], red[1][k]), fmaxf(red[2][k], red[3][k]));
    float b = fmaxf(fmaxf(red[0][8 + k], red[1][8 + k]), fmaxf(red[2][8 + k], red[3][8 + k]));
    float c = fminf(fminf(red[0][16 + k], red[1][16 + k]), fminf(red[2][16 + k], red[3][16 + k]));
    float d = fminf(fminf(red[0][24 + k], red[1][24 + k]), fminf(red[2][24 + k], red[3][24 + k]));
    int slot = (n * K_ + k0 + k) * HS_ + hs;
    accA[slot] = a; accB[slot] = b; accC[slot] = c; accD[slot] = d;
  }
}

// Kernel D: combine hw-splits, apply sqrt (monotone => exchange with max/min),
// triplet margin, deterministic tree-sum, mean.
__global__ __launch_bounds__(256) void k_final(
    const float* __restrict__ accA, const float* __restrict__ accB,
    const float* __restrict__ accC, const float* __restrict__ accD,
    const float* __restrict__ ksq, float* __restrict__ out)
{
  int tid = threadIdx.x;
  float local = 0.0f;
  for (int i = tid; i < N_ * K_; i += 256) {
    int k = i & (K_ - 1);
    float a = NEGBIG, b = NEGBIG, c = POSBIG, d = POSBIG;
    #pragma unroll
    for (int hsv = 0; hsv < HS_; ++hsv) {
      int slot = i * HS_ + hsv;
      a = fmaxf(a, accA[slot]); b = fmaxf(b, accB[slot]);
      c = fminf(c, accC[slot]); d = fminf(d, accD[slot]);
    }
    float ks = ksq[k];
    float pos; bool hasp = false;
    pos = -1e30f;
    if (a > -2.9e38f) { pos = sqrtf(fmaxf(ks + a, 1e-12f)); hasp = true; }
    if (b > -2.9e38f) {
      float t2 = sqrtf(fmaxf(ks + b, 1e-12f)) - 5.0f;
      pos = hasp ? fmaxf(pos, t2) : t2;
    }
    float neg = 1e30f; bool hasn = false;
    if (c < 2.9e38f) { neg = sqrtf(fmaxf(ks + c, 1e-12f)); hasn = true; }
    if (d < 2.9e38f) {
      float t2 = sqrtf(fmaxf(ks + d, 1e-12f)) + 5.0f;
      neg = hasn ? fminf(neg, t2) : t2;
    }
    local += fmaxf(pos - neg + 1.0f, 0.0f);
  }
  __shared__ float sh[256];
  sh[tid] = local;
  __syncthreads();
  for (int o = 128; o > 0; o >>= 1) {
    if (tid < o) sh[tid] += sh[tid + o];
    __syncthreads();
  }
  if (tid == 0) out[0] = sh[0] * (1.0f / (N_ * K_));
}

extern "C" void kernel_launch(void* const* d_in, const int* in_sizes, int n_in,
                              void* d_out, int out_size, void* d_ws, size_t ws_size,
                              hipStream_t stream) {
  const float* kp1   = (const float*)d_in[0];
  const float* desc1 = (const float*)d_in[1];
  const float* desc2 = (const float*)d_in[2];
  const float* homo  = (const float*)d_in[3];
  const float* vis   = (const float*)d_in[4];
  float* out = (float*)d_out;

  float* ws = (float*)d_ws;
  float* kpgx = ws;                  // K
  float* kpgy = kpgx + K_;           // K
  float* ksq  = kpgy + K_;           // K
  float* kpd  = ksq + K_;            // K*C
  float* wxa  = kpd + K_ * C_;       // N*HW
  float* wya  = wxa + N_ * HW_;      // N*HW
  float* vma  = wya + N_ * HW_;      // N*HW
  float* dsa  = vma + N_ * HW_;      // N*HW
  float* accA = dsa + N_ * HW_;      // N*K*HS
  float* accB = accA + N_ * K_ * HS_;
  float* accC = accB + N_ * K_ * HS_;
  float* accD = accC + N_ * K_ * HS_;

  hipLaunchKernelGGL(k_sample, dim3(K_ * C_ / 256), dim3(256), 0, stream,
                     kp1, desc1, out + 1, kpd, ksq, kpgx, kpgy);
  hipLaunchKernelGGL(k_prep, dim3((N_ * HW_ + 255) / 256), dim3(256), 0, stream,
                     desc2, homo, vis, wxa, wya, vma, dsa);
  hipLaunchKernelGGL(k_main, dim3(N_ * (K_ / KT_) * HS_), dim3(256), 0, stream,
                     desc2, kpd, kpgx, kpgy, wxa, wya, vma, dsa,
                     accA, accB, accC, accD);
  hipLaunchKernelGGL(k_final, dim3(1), dim3(256), 0, stream,
                     accA, accB, accC, accD, ksq, out);
}

// Round 2
// 56.940 us; speedup vs baseline: 4.6265x; 4.6265x over previous
//
#include <hip/hip_runtime.h>
#include <math.h>

namespace {
constexpr int N_ = 2, C_ = 64, HR_ = 60, WR_ = 80, HW_ = HR_ * WR_; // 4800
constexpr int K_ = 1024, GS_ = 8, H_ = HR_ * GS_, W_ = WR_ * GS_;  // 480, 640
constexpr int KT_ = 16, HS_ = 8, SEG_ = HW_ / HS_;                 // 600
constexpr float NEGBIG = -3.0e38f, POSBIG = 3.0e38f;
}

// Kernel A: bilinear sample desc1 at keypoints; one thread per (k, c).
// Also emits ||kp1_desc[k]||^2 (wave reduction; one wave == one keypoint)
// and the kp_grid coords with the reference's .at[:,0]/.at[:,1] quirk
// (only keypoints 0 and 1 are divided by GS).
__global__ __launch_bounds__(256) void k_sample(
    const float* __restrict__ kp1, const float* __restrict__ desc1,
    float* __restrict__ out_desc, float* __restrict__ kpd,
    float* __restrict__ ksq, float* __restrict__ kpgx, float* __restrict__ kpgy)
{
  int t = blockIdx.x * 256 + threadIdx.x;
  int k = t >> 6, c = t & 63;
  float bf = kp1[k * 4 + 0];
  float yr = kp1[k * 4 + 2];
  float xr = kp1[k * 4 + 3];
  int b = (int)bf;
  float x = fminf(fmaxf(xr * (1.0f / GS_), 0.0f), (float)(WR_ - 1));
  float y = fminf(fmaxf(yr * (1.0f / GS_), 0.0f), (float)(HR_ - 1));
  float x0f = floorf(x), y0f = floorf(y);
  float x1f = fminf(x0f + 1.0f, (float)(WR_ - 1));
  float y1f = fminf(y0f + 1.0f, (float)(HR_ - 1));
  float wx = x - x0f, wy = y - y0f;
  int x0 = (int)x0f, x1 = (int)x1f, y0 = (int)y0f, y1 = (int)y1f;
  const float* dbase = desc1 + ((size_t)b * C_ + c) * HW_;
  float v00 = dbase[y0 * WR_ + x0], v01 = dbase[y0 * WR_ + x1];
  float v10 = dbase[y1 * WR_ + x0], v11 = dbase[y1 * WR_ + x1];
  float v = (1.0f - wy) * ((1.0f - wx) * v00 + wx * v01)
          + wy * ((1.0f - wx) * v10 + wx * v11);
  out_desc[k * C_ + c] = v;
  kpd[k * C_ + c] = v;
  float sq = v * v;
  #pragma unroll
  for (int m = 1; m < 64; m <<= 1) sq += __shfl_xor(sq, m);
  if (c == 0) {
    ksq[k] = sq;
    // Reference quirk: kp_grid.at[:,0] / .at[:,1] index the KEYPOINT axis,
    // so only keypoints 0 and 1 get divided by GS.
    kpgx[k] = (k < 2) ? xr * (1.0f / GS_) : xr;
    kpgy[k] = (k < 2) ? yr * (1.0f / GS_) : yr;
  }
}

// Kernel B: per (n, hw): warped grid coords, visibility product over 8x8 cell,
// and ||desc2[n,:,hw]||^2.
__global__ __launch_bounds__(256) void k_prep(
    const float* __restrict__ desc2, const float* __restrict__ homo,
    const float* __restrict__ vis,
    float* __restrict__ wxa, float* __restrict__ wya,
    float* __restrict__ vma, float* __restrict__ dsa)
{
  int t = blockIdx.x * 256 + threadIdx.x;
  if (t >= N_ * HW_) return;
  int n = t / HW_, hw = t % HW_;
  int h = hw / WR_, w = hw % WR_;
  float gx = (float)(w * GS_ + GS_ / 2);
  float gy = (float)(h * GS_ + GS_ / 2);
  const float* hm = homo + n * 9;
  float w0 = fmaf(hm[0], gx, fmaf(hm[1], gy, hm[2]));
  float w1 = fmaf(hm[3], gx, fmaf(hm[4], gy, hm[5]));
  float w2 = fmaf(hm[6], gx, fmaf(hm[7], gy, hm[8]));
  wxa[t] = w0 / w2;
  wya[t] = w1 / w2;
  const float* vb = vis + (size_t)n * H_ * W_ + (size_t)(h * GS_) * W_ + w * GS_;
  float p = 1.0f;
  #pragma unroll
  for (int i = 0; i < GS_; i++)
    #pragma unroll
    for (int j = 0; j < GS_; j++) p *= vb[i * W_ + j];
  vma[t] = p;
  const float* d2 = desc2 + (size_t)n * C_ * HW_ + hw;
  float s = 0.0f;
  #pragma unroll
  for (int c = 0; c < C_; c++) { float dv = d2[c * HW_]; s = fmaf(dv, dv, s); }
  dsa[t] = s;
}

// Kernel C: main reduction. Block = (n, tile of 16 keypoints, 1/8 of hw).
// Each thread holds one desc2 column (64 floats) in registers. Keypoint
// descriptors are read through WAVE-UNIFORM addresses -> compiler emits
// s_load + v_fmac with an SGPR operand (no LDS in the inner loop, low VGPR
// pressure, no spills). dist=sqrt inline (16 sqrts vs 1024 FMAs: noise).
__global__ __launch_bounds__(256) void k_main(
    const float* __restrict__ desc2,
    const float* __restrict__ kpd, const float* __restrict__ kpgx,
    const float* __restrict__ kpgy, const float* __restrict__ ksq,
    const float* __restrict__ wxa, const float* __restrict__ wya,
    const float* __restrict__ vma, const float* __restrict__ dsa,
    float* __restrict__ accP, float* __restrict__ accN)
{
  __shared__ float redP[4][KT_], redN[4][KT_];
  int tid = threadIdx.x;
  int bx = blockIdx.x;
  int n = bx / ((K_ / KT_) * HS_);
  int rem = bx % ((K_ / KT_) * HS_);
  int kt = rem / HS_, hs = rem % HS_;
  int k0 = kt * KT_;

  float mP[KT_], mN[KT_];
  #pragma unroll
  for (int k = 0; k < KT_; k++) { mP[k] = NEGBIG; mN[k] = POSBIG; }

  const float* dbase = desc2 + (size_t)n * C_ * HW_;
  const float* wxp = wxa + n * HW_;
  const float* wyp = wya + n * HW_;
  const float* vmp = vma + n * HW_;
  const float* dsp = dsa + n * HW_;
  int hwb = hs * SEG_;

  for (int ch = 0; ch < (SEG_ + 255) / 256; ++ch) {
    int off = ch * 256 + tid;
    bool valid = off < SEG_;
    int hw = hwb + (valid ? off : 0);
    float dcol[C_];
    #pragma unroll
    for (int c = 0; c < C_; c++) dcol[c] = dbase[c * HW_ + hw];
    float wxv = wxp[hw], wyv = wyp[hw], dsv = dsp[hw];
    float vm5 = (vmp[hw] != 0.0f) ? 5.0f : 0.0f;
    #pragma unroll
    for (int k = 0; k < KT_; k++) {
      const float* kb = kpd + (k0 + k) * C_;  // wave-uniform -> s_load
      float s0 = 0.f, s1 = 0.f, s2 = 0.f, s3 = 0.f;
      #pragma unroll
      for (int q = 0; q < 16; q++) {
        s0 = fmaf(kb[4 * q + 0], dcol[4 * q + 0], s0);
        s1 = fmaf(kb[4 * q + 1], dcol[4 * q + 1], s1);
        s2 = fmaf(kb[4 * q + 2], dcol[4 * q + 2], s2);
        s3 = fmaf(kb[4 * q + 3], dcol[4 * q + 3], s3);
      }
      float dot = (s0 + s1) + (s2 + s3);
      float d2v = fmaxf(ksq[k0 + k] + dsv - 2.0f * dot, 1e-12f);
      float dist = sqrtf(d2v);
      float dx = kpgx[k0 + k] - wxv, dy = kpgy[k0 + k] - wyv;
      bool inside = fmaf(dx, dx, dy * dy) <= 56.25f;  // (GS-0.5)^2
      float posv = dist - (inside ? 0.0f : vm5);
      float negv = dist + (inside ? vm5 : 0.0f);
      if (valid) { mP[k] = fmaxf(mP[k], posv); mN[k] = fminf(mN[k], negv); }
    }
  }

  // wave butterfly reduction (64 lanes)
  #pragma unroll
  for (int k = 0; k < KT_; k++) {
    #pragma unroll
    for (int m = 1; m < 64; m <<= 1) {
      mP[k] = fmaxf(mP[k], __shfl_xor(mP[k], m));
      mN[k] = fminf(mN[k], __shfl_xor(mN[k], m));
    }
  }
  int wave = tid >> 6, lane = tid & 63;
  if (lane == 0) {
    #pragma unroll
    for (int k = 0; k < KT_; k++) { redP[wave][k] = mP[k]; redN[wave][k] = mN[k]; }
  }
  __syncthreads();
  if (tid < KT_) {
    int k = tid;
    float p = fmaxf(fmaxf(redP[0][k], redP[1][k]), fmaxf(redP[2][k], redP[3][k]));
    float q = fminf(fminf(redN[0][k], redN[1][k]), fminf(redN[2][k], redN[3][k]));
    int slot = (n * K_ + k0 + k) * HS_ + hs;
    accP[slot] = p; accN[slot] = q;
  }
}

// Kernel D: combine hw-splits, triplet margin, deterministic tree-sum, mean.
__global__ __launch_bounds__(256) void k_final(
    const float* __restrict__ accP, const float* __restrict__ accN,
    float* __restrict__ out)
{
  int tid = threadIdx.x;
  float local = 0.0f;
  for (int i = tid; i < N_ * K_; i += 256) {
    float p = NEGBIG, q = POSBIG;
    #pragma unroll
    for (int hsv = 0; hsv < HS_; ++hsv) {
      int slot = i * HS_ + hsv;
      p = fmaxf(p, accP[slot]);
      q = fminf(q, accN[slot]);
    }
    local += fmaxf(p - q + 1.0f, 0.0f);
  }
  __shared__ float sh[256];
  sh[tid] = local;
  __syncthreads();
  for (int o = 128; o > 0; o >>= 1) {
    if (tid < o) sh[tid] += sh[tid + o];
    __syncthreads();
  }
  if (tid == 0) out[0] = sh[0] * (1.0f / (N_ * K_));
}

extern "C" void kernel_launch(void* const* d_in, const int* in_sizes, int n_in,
                              void* d_out, int out_size, void* d_ws, size_t ws_size,
                              hipStream_t stream) {
  const float* kp1   = (const float*)d_in[0];
  const float* desc1 = (const float*)d_in[1];
  const float* desc2 = (const float*)d_in[2];
  const float* homo  = (const float*)d_in[3];
  const float* vis   = (const float*)d_in[4];
  float* out = (float*)d_out;

  float* ws = (float*)d_ws;
  float* kpgx = ws;                  // K
  float* kpgy = kpgx + K_;           // K
  float* ksq  = kpgy + K_;           // K
  float* kpd  = ksq + K_;            // K*C
  float* wxa  = kpd + K_ * C_;       // N*HW
  float* wya  = wxa + N_ * HW_;      // N*HW
  float* vma  = wya + N_ * HW_;      // N*HW
  float* dsa  = vma + N_ * HW_;      // N*HW
  float* accP = dsa + N_ * HW_;      // N*K*HS
  float* accN = accP + N_ * K_ * HS_;

  hipLaunchKernelGGL(k_sample, dim3(K_ * C_ / 256), dim3(256), 0, stream,
                     kp1, desc1, out + 1, kpd, ksq, kpgx, kpgy);
  hipLaunchKernelGGL(k_prep, dim3((N_ * HW_ + 255) / 256), dim3(256), 0, stream,
                     desc2, homo, vis, wxa, wya, vma, dsa);
  hipLaunchKernelGGL(k_main, dim3(N_ * (K_ / KT_) * HS_), dim3(256), 0, stream,
                     desc2, kpd, kpgx, kpgy, ksq, wxa, wya, vma, dsa, accP, accN);
  hipLaunchKernelGGL(k_final, dim3(1), dim3(256), 0, stream,
                     accP, accN, out);
}